// Round 5
// baseline (107.166 us; speedup 1.0000x reference)
//
#include <hip/hip_runtime.h>
#include <math.h>

#define HW 1024
#define NB 16
#define TMAXS 1024

typedef unsigned long long ull;

__device__ __forceinline__ double u2d(ull u) {
  return __longlong_as_double((long long)u);
}
__device__ __forceinline__ ull d2u(double d) {
  return (ull)__double_as_longlong(d);
}

// key = exp(-(0.5*g + 0.5*h)/sqrt(32)) with pre-halved operands (validated
// bit-exact vs reference rounds 0-4: same f32 op chain, contract off).
__device__ __forceinline__ float keyhalf(float gh, float hh) {
#pragma clang fp contract(off)
  const float INV = 0.17677669529663687f; // fl32(1/sqrt(32))
  return expf(-(gh + hh) * INV);
}

// (f32 key bits : 32 | (1023-idx) : 10) as u64 — order & ties bit-identical
// to the validated f64 packing; reinterpreted as f64 it is nonneg/non-NaN
// (key in [0,1] -> exp field <= 0x3F8), so the fmax DPP chain applies.
__device__ __forceinline__ ull packkey(float keyf, int idx) {
  return ((ull)__float_as_uint(keyf) << 32) | (ull)(1023 - idx);
}

// One DPP reduction stage on a packed value (nonnegative as f64; disabled
// source lanes contribute 0.0 = identity). Chain validated all rounds.
template <int CTRL>
__device__ __forceinline__ double dpp_fmax64(double x) {
  ull u = d2u(x);
  int lo = (int)(unsigned)u;
  int hi = (int)(unsigned)(u >> 32);
  int lo2 = __builtin_amdgcn_update_dpp(0, lo, CTRL, 0xF, 0xF, false);
  int hi2 = __builtin_amdgcn_update_dpp(0, hi, CTRL, 0xF, 0xF, false);
  double y = u2d(((ull)(unsigned)hi2 << 32) | (unsigned)lo2);
  return fmax(x, y);
}

// DPP min-u32 stage (nonneg f32 bits: u32 order == float order; identity =
// +inf bits for bound-off lanes). PREDICTION-ONLY (never affects semantics).
template <int CTRL>
__device__ __forceinline__ unsigned dpp_minu32(unsigned x) {
  int s = __builtin_amdgcn_update_dpp(0x7F800000, (int)x, CTRL, 0xF, 0xF,
                                      false);
  unsigned u = (unsigned)s;
  return (x < u) ? x : u;
}

__device__ __forceinline__ ull rdl64(double d, int l) {
  ull u = d2u(d);
  int lo = __builtin_amdgcn_readlane((int)(unsigned)u, l);
  int hi = __builtin_amdgcn_readlane((int)(unsigned)(u >> 32), l);
  return ((ull)(unsigned)hi << 32) | (unsigned)lo;
}

// SALU neighbor-validity mask. lanes: 0,1,2 = top row; 0,3,5 = left col;
// 2,4,7 = right col; 5,6,7 = bottom row.
__device__ __forceinline__ unsigned vmask_of(int cell) {
  unsigned m = 0xFFu;
  const int r = cell >> 5, c = cell & 31;
  if (r == 0) m &= ~0x07u;
  if (r == 31) m &= ~0xE0u;
  if (c == 0) m &= ~0x29u;
  if (c == 31) m &= ~0x94u;
  return m;
}

// ---------------------------------------------------------------------------
// Fused per-batch A* + backtrack, one wave per batch.
// R5 = R4's validated split-fold structure + NEXT-SEL SPECULATIVE PREFETCH.
//
// Exact selection (unchanged semantics): per iter, winner = max over
//   stale'(64, gp excluded) ∪ patched-group(16) ∪ fresh pk(<=8)
// computed as three folds: MA (6-stage, register stale), GC (4-stage over
// patched group keys), PB (3-stage over fresh pk), merged with exact u64
// compares (== nonneg-f64 order, idx bits break ties; no cross-cell equal
// packed values possible except identical (key,idx) duplicates, which max
// ignores).  Group rebuild = R0-style zero + 16 ds_max_u64 (lane31's fold
// value is NOT stored — it feeds GC only), then fresh-pk atomics, then the
// stale snapshot (same-array program order = validated hazard rules).
//
// Speculation (PERF-ONLY, exactness never depends on it): the next winner
// is one of
//   spec1 = cell of max(MA, GC)      (exact, non-fresh side)
//   spec2 = fresh-relax winner: all fresh keys share g2h, so exact order
//           is ascending hh (nv.z bits), tie -> lower n (lane order is
//           monotone in n).  Differs from exact only on exp-bit collisions
//           -> at worst a MISS, handled by the fallback read path.
// At iter end, AFTER this iter's cellT writes (relax + pop flags) and key2
// writes (pk + denorm), issue all three read groups for both candidates;
// wave DS ops are in-order, so prefetched data == LDS state at next iter
// start.  At the head, a uniform select picks prefetched registers (hit)
// or re-reads (miss, identical to R4's path).
// ---------------------------------------------------------------------------
extern "C" __global__ void __launch_bounds__(64) astar_fused(
    const float* __restrict__ cm_g, const float* __restrict__ sm_g,
    const float* __restrict__ gm_g, const float* __restrict__ om_g,
    float* __restrict__ out) {
#pragma clang fp contract(off)
  const int b = blockIdx.x;
  const int lane = threadIdx.x;

  __shared__ __align__(16) uint4 cellT[HW];  // {g, cm, hw, flg}
  __shared__ __align__(16) ull key2[HW];     // packed (f32keybits | 1023-idx)
  __shared__ __align__(16) unsigned par[HW]; // parent | mark bit31
  __shared__ __align__(16) ull level1[64];   // per-16-cell-group max
  const float2* cell2 = (const float2*)cellT; // {g, cm} pairs (stride 2)
  unsigned* cellu = (unsigned*)cellT;

  const float* cm = cm_g + b * HW;
  const float* sm = sm_g + b * HW;
  const float* gm = gm_g + b * HW;
  const float* om = om_g + b * HW;

  // ---- init pass 1: vectorized loads, locate goal/start ----
  float4 c4[4], o4[4];
  int gi = -1, si = -1;
#pragma unroll
  for (int q = 0; q < 4; ++q) {
    const int base = q * 256 + lane * 4;
    c4[q] = *(const float4*)(cm + base);
    o4[q] = *(const float4*)(om + base);
    const float4 s4 = *(const float4*)(sm + base);
    const float4 g4 = *(const float4*)(gm + base);
    const float sv[4] = {s4.x, s4.y, s4.z, s4.w};
    const float gv[4] = {g4.x, g4.y, g4.z, g4.w};
#pragma unroll
    for (int j = 0; j < 4; ++j) {
      if (gv[j] > 0.5f) gi = base + j;
      if (sv[j] > 0.5f) si = base + j;
    }
  }
#pragma unroll
  for (int m = 32; m >= 1; m >>= 1) {
    const int og = __shfl_xor(gi, m, 64);
    const int os = __shfl_xor(si, m, 64);
    gi = (og > gi) ? og : gi;
    si = (os > si) ? os : si;
  }
  const int goal = __builtin_amdgcn_readfirstlane(gi);
  const int start = __builtin_amdgcn_readfirstlane(si);

  // ---- init pass 2: h (exact ref op order), cell structs, key2, level1 ----
  level1[lane] = 0ull; // before the atomics below (same array: order kept)
  const float grf = (float)(goal >> 5), gcf = (float)(goal & 31);
#pragma unroll
  for (int q = 0; q < 4; ++q) {
    const int base = q * 256 + lane * 4;
    const float cv[4] = {c4[q].x, c4[q].y, c4[q].z, c4[q].w};
    const float ov[4] = {o4[q].x, o4[q].y, o4[q].z, o4[q].w};
    ull pk[4];
#pragma unroll
    for (int j = 0; j < 4; ++j) {
      const int cell = base + j;
      const float rr = (float)(cell >> 5), cc = (float)(cell & 31);
      const float dr = fabsf(rr - grf), dc = fabsf(cc - gcf);
      const float h0 = (dr + dc) - fminf(dr, dc); // exact (small ints)
      const float euc = sqrtf(dr * dr + dc * dc); // exact radicand
      const float t1 = 0.001f * euc;              // contract off: no fma
      const float hh = h0 + t1;
      const float hf = hh + cv[j]; // h_full (h + cm), exact ref order
      const float hw = 0.5f * hf;  // exact scaling
      unsigned fv = (ov[j] > 0.5f) ? 1u : 0u;
      pk[j] = (ull)(1023 - cell);
      if (cell == start) {
        fv |= 2u; // open = start map
        pk[j] = packkey(keyhalf(0.0f, hw), cell);
      }
      cellT[cell] = make_uint4(__float_as_uint(0.0f), __float_as_uint(cv[j]),
                               __float_as_uint(hw), fv);
      atomicMax(&level1[cell >> 4], pk[j]);
    }
    *(uint4*)&par[base] =
        make_uint4((unsigned)goal, (unsigned)goal, (unsigned)goal, (unsigned)goal);
    ulonglong2 k01, k23;
    k01.x = pk[0]; k01.y = pk[1];
    k23.x = pk[2]; k23.y = pk[3];
    *(ulonglong2*)&key2[base] = k01;
    *(ulonglong2*)&key2[base + 2] = k23;
  }
  __builtin_amdgcn_wave_barrier();
  ull stale = level1[lane]; // S_{-1} group maxes

  int dlt = 0;
  if (lane < 8) {
    const int k = (lane < 4) ? lane : lane + 1; // skip center
    dlt = (k / 3 - 1) * 32 + (k % 3 - 1);       // monotone increasing in lane
  }

  int sel = start; // step-0 argmax: start is the only open cell
  bool reached = false;

  // speculation state (perf-only)
  int spec1 = -1, spec2 = -1;
  float2 sg1p = make_float2(0.f, 0.f), sg2p = make_float2(0.f, 0.f);
  uint4 nv1p = make_uint4(0u, 0u, 0u, 0u), nv2p = make_uint4(0u, 0u, 0u, 0u);
  ull gco1p = 0ull, gco2p = 0ull;

#pragma unroll 1
  for (int step = 0; step < TMAXS; ++step) {
    if (sel == goal) { reached = true; break; }
    const int gp = sel >> 4;
    const unsigned vmask = vmask_of(sel);
    const int n = sel + dlt;
    const bool relaxer = (lane < 8) && ((vmask >> lane) & 1u);
    const bool gcl = (lane >= 16) && (lane < 32);
    const int gcell = gp * 16 + (lane - 16);

    // zero the popped group BEFORE the rebuild atomics (R0-validated form)
    if (lane == 16) level1[gp] = 0ull;

    // -- data acquire: prefetched on hit (state-exact: reads were issued
    //    after ALL prev-iter writes, wave DS ops in-order), else read now --
    const bool h1 = (sel == spec1), h2 = (sel == spec2);
    float2 sg; uint4 nv; ull gco;
    if (h1) {
      sg = sg1p; nv = nv1p; gco = gco1p;
    } else if (h2) {
      sg = sg2p; nv = nv2p; gco = gco2p;
    } else {
      sg = cell2[2 * sel];
      nv = make_uint4(0u, 0u, 0u, 0u);
      if (relaxer) nv = cellT[n];
      gco = 0ull;
      if (gcl) gco = key2[gcell];
    }

    // -- chain A: 6-stage fold over stale' (gp excluded) --
    double ma = (lane == gp) ? 0.0 : u2d(stale);
    ma = dpp_fmax64<0x111>(ma); // row_shr:1
    ma = dpp_fmax64<0x112>(ma); // row_shr:2
    ma = dpp_fmax64<0x114>(ma); // row_shr:4
    ma = dpp_fmax64<0x118>(ma); // row_shr:8
    ma = dpp_fmax64<0x142>(ma); // row_bcast:15
    ma = dpp_fmax64<0x143>(ma); // row_bcast:31 -> lane63 = max(all)

    // -- relax predicate + early cellT/par writes (pre-exp) --
    const float g2full = sg.x + sg.y; // g[sel] + cm[sel], exact ref order
    const float g2h = 0.5f * g2full;  // exact scaling
    const unsigned f = nv.w;
    const bool updv =
        relaxer && (f & 1u) &&
        (((f & 6u) == 0u) || (((f & 2u) != 0u) && (__uint_as_float(nv.x) > g2full)));
    if (updv) {
      cellT[n] = make_uint4(__float_as_uint(g2full), nv.y, nv.z, f | 2u);
      par[n] = (unsigned)sel;
    }
    if (lane == 8) {
      cellu[4 * sel + 3] = 5u;       // pop: free|hist (validated const)
      key2[sel] = (ull)(1023 - sel); // denormal entry
    }

    // -- group rebuild: patch + 16 atomics (after the zero) --
    ull gcp = gco;
    if (gcl && gcell == sel) gcp = (ull)(1023 - sel);
    if (gcl) atomicMax(&level1[gp], gcp);

    // -- chain C: 4-stage fold over patched group keys -> lane31 --
    double mc = gcl ? u2d(gcp) : 0.0;
    mc = dpp_fmax64<0x111>(mc);
    mc = dpp_fmax64<0x112>(mc);
    mc = dpp_fmax64<0x114>(mc);
    mc = dpp_fmax64<0x118>(mc);

    // -- spec2 prediction (pre-exp, prediction-only): fresh winner =
    //    min hh (u32 bits), tie -> lowest lane (== lowest n) --
    const unsigned hb = updv ? nv.z : 0x7F800000u;
    unsigned mh = hb;
    mh = dpp_minu32<0x111>(mh);
    mh = dpp_minu32<0x112>(mh);
    mh = dpp_minu32<0x114>(mh); // lane7 = min over lanes 0..7
    const unsigned MH = (unsigned)__builtin_amdgcn_readlane((int)mh, 7);
    const bool valid2 = (MH != 0x7F800000u);
    const ull bal = __ballot(updv && (hb == MH));
    int l2 = (int)__ffsll(bal) - 1;
    if (l2 < 0) l2 = 0;
    const int s2 = __builtin_amdgcn_readlane(n, l2);

    // -- spec2 cellT-side prefetch (after this iter's cellT writes) --
    const unsigned vm2 = vmask_of(s2);
    const bool rel2 = (lane < 8) && ((vm2 >> lane) & 1u);
    sg2p = cell2[2 * s2];
    nv2p = make_uint4(0u, 0u, 0u, 0u);
    if (rel2) nv2p = cellT[s2 + dlt];

    // -- exp + pk + key2/level1 maintenance --
    ull pk = 0ull;
    if (updv) pk = packkey(keyhalf(g2h, __uint_as_float(nv.z)), n);
    if (updv) key2[n] = pk;
    if (updv) atomicMax(&level1[n >> 4], pk);
    const ull stale_n = level1[lane]; // after ALL level1 updates (in-order)

    // -- spec2 key2-side prefetch (after ALL key2 writes this iter) --
    gco2p = 0ull;
    if (gcl) gco2p = key2[(s2 >> 4) * 16 + (lane - 16)];

    // -- chain B: 3-stage fold over fresh pk -> lane7 --
    double mb = updv ? u2d(pk) : 0.0;
    mb = dpp_fmax64<0x111>(mb);
    mb = dpp_fmax64<0x112>(mb);
    mb = dpp_fmax64<0x114>(mb);

    // -- exact merge (u64 compares == nonneg-f64 order, same ties) --
    const ull GC = rdl64(mc, 31);
    const ull MA = rdl64(ma, 63);
    const ull PB = rdl64(mb, 7);
    const ull MACv = (GC > MA) ? GC : MA;
    const ull M = (PB > MACv) ? PB : MACv;
    const int nsel = 1023 - (int)((unsigned)M & 1023u);
    const int s1 = 1023 - (int)((unsigned)MACv & 1023u);

    // -- spec1 prefetch (all writes this iter already done) --
    const unsigned vm1 = vmask_of(s1);
    const bool rel1 = (lane < 8) && ((vm1 >> lane) & 1u);
    sg1p = cell2[2 * s1];
    nv1p = make_uint4(0u, 0u, 0u, 0u);
    if (rel1) nv1p = cellT[s1 + dlt];
    gco1p = 0ull;
    if (gcl) gco1p = key2[(s1 >> 4) * 16 + (lane - 16)];

    spec1 = s1;
    spec2 = valid2 ? s2 : -1;
    stale = stale_n;
    sel = nsel;
    __builtin_amdgcn_wave_barrier();
  }
  if (reached && lane == 0) cellu[4 * goal + 3] |= 4u; // hist includes goal
  __builtin_amdgcn_wave_barrier();

  // ---- fused backtrack (lane 0): mark path via par bit31 ----
  if (lane == 0) {
    const unsigned pv = par[goal];
    par[goal] = pv | 0x80000000u; // path starts as goal one-hot
    unsigned loc = pv & 1023u;
#pragma unroll 1
    for (int i = 0; i < HW; ++i) {
      const unsigned w = par[loc];
      if (w & 0x80000000u) break; // deterministic replay of marked cells
      par[loc] = w | 0x80000000u;
      loc = w & 1023u;
    }
  }
  __builtin_amdgcn_wave_barrier();

  // ---- epilogue: hist + path ----
#pragma unroll
  for (int q = 0; q < 4; ++q) {
    const int base = q * 256 + lane * 4;
    float4 hv, pv;
    hv.x = (cellu[4 * (base + 0) + 3] & 4u) ? 1.0f : 0.0f;
    hv.y = (cellu[4 * (base + 1) + 3] & 4u) ? 1.0f : 0.0f;
    hv.z = (cellu[4 * (base + 2) + 3] & 4u) ? 1.0f : 0.0f;
    hv.w = (cellu[4 * (base + 3) + 3] & 4u) ? 1.0f : 0.0f;
    pv.x = (par[base + 0] >> 31) ? 1.0f : 0.0f;
    pv.y = (par[base + 1] >> 31) ? 1.0f : 0.0f;
    pv.z = (par[base + 2] >> 31) ? 1.0f : 0.0f;
    pv.w = (par[base + 3] >> 31) ? 1.0f : 0.0f;
    *(float4*)(out + b * HW + base) = hv;
    *(float4*)(out + NB * HW + b * HW + base) = pv;
  }
}

extern "C" void kernel_launch(void* const* d_in, const int* in_sizes, int n_in,
                              void* d_out, int out_size, void* d_ws,
                              size_t ws_size, hipStream_t stream) {
  const float* cm = (const float*)d_in[0];
  const float* sm = (const float*)d_in[1];
  const float* gm = (const float*)d_in[2];
  const float* om = (const float*)d_in[3];
  float* out = (float*)d_out;
  hipLaunchKernelGGL(astar_fused, dim3(NB), dim3(64), 0, stream, cm, sm, gm,
                     om, out);
}

// Round 6
// 79.347 us; speedup vs baseline: 1.3506x; 1.3506x over previous
//
#include <hip/hip_runtime.h>
#include <math.h>

#define HW 1024
#define NB 16
#define TMAXS 1024

typedef unsigned long long ull;

__device__ __forceinline__ double u2d(ull u) {
  return __longlong_as_double((long long)u);
}
__device__ __forceinline__ ull d2u(double d) {
  return (ull)__double_as_longlong(d);
}

// key = exp(-(0.5*g + 0.5*h)/sqrt(32)) with pre-halved operands (validated
// bit-exact vs reference rounds 0-5: same f32 op chain, contract off).
__device__ __forceinline__ float keyhalf(float gh, float hh) {
#pragma clang fp contract(off)
  const float INV = 0.17677669529663687f; // fl32(1/sqrt(32))
  return expf(-(gh + hh) * INV);
}

// (f32 key bits : 32 | (1023-idx) : 10) as u64 — order & ties bit-identical
// to the validated f64 packing; reinterpreted as f64 it is nonneg/non-NaN
// (key in [0,1] -> exp field <= 0x3F8), so the fmax DPP chain applies.
__device__ __forceinline__ ull packkey(float keyf, int idx) {
  return ((ull)__float_as_uint(keyf) << 32) | (ull)(1023 - idx);
}

// One DPP reduction stage on a packed value (nonnegative as f64; disabled
// source lanes contribute 0.0 = identity). Chain validated all rounds.
template <int CTRL>
__device__ __forceinline__ double dpp_fmax64(double x) {
  ull u = d2u(x);
  int lo = (int)(unsigned)u;
  int hi = (int)(unsigned)(u >> 32);
  int lo2 = __builtin_amdgcn_update_dpp(0, lo, CTRL, 0xF, 0xF, false);
  int hi2 = __builtin_amdgcn_update_dpp(0, hi, CTRL, 0xF, 0xF, false);
  double y = u2d(((ull)(unsigned)hi2 << 32) | (unsigned)lo2);
  return fmax(x, y);
}

__device__ __forceinline__ ull rdl64(double d, int l) {
  ull u = d2u(d);
  int lo = __builtin_amdgcn_readlane((int)(unsigned)u, l);
  int hi = __builtin_amdgcn_readlane((int)(unsigned)(u >> 32), l);
  return ((ull)(unsigned)hi << 32) | (unsigned)lo;
}

// ---------------------------------------------------------------------------
// Fused per-batch A* + backtrack, one wave per batch.
// R6 = R4 (best measured: ~37.1 µs astar) with ONE change: the B/C fold is
// split so nothing group/stale-side waits on the exp chain.
//   R5's speculation regressed (52 µs): spec1's address depends on the final
//   merge, so its prefetch hid nothing while adding ~40 in-order DS ops/iter
//   ahead of the next iteration's critical reads. Reverted entirely.
// Argmax decomposition (multiset unchanged => bit-identical winner):
//   chain A (6-stage DPP) over register stale' (gp excluded)  -> MA, pre-exp
//   chain C (4-stage DPP) over patched group keys             -> GC, pre-exp
//           lane31 of chain C = rebuilt group max, stored to level1[gp]
//           (replaces zero + 16 atomics; R4-validated)
//   MACv = max(GC, MA)  — resolved while exp is still in flight
//   chain B (3-stage DPP, lanes 0..7 only) over fresh pk      -> PB, post-exp
//   sel = idx of max(PB, MACv)   (exact u64 compares == nonneg-f64 order,
//   idx bits break ties — validated all rounds)
// Post-exp tail: 3 DPP stages + 2 readlanes + 1 compare (was 4 stages +
// 6 readlanes + max3 in R4).
// DS program order per iter (identical to R4): reads(cell2[sel] b64,
// cellT[n] b128, key2 group) -> writes(cellT/par pre-exp; pop flag+denorm;
// key2[n] post-exp) -> level1[gp] store -> relax atomicMax -> stale read.
// ---------------------------------------------------------------------------
extern "C" __global__ void __launch_bounds__(64) astar_fused(
    const float* __restrict__ cm_g, const float* __restrict__ sm_g,
    const float* __restrict__ gm_g, const float* __restrict__ om_g,
    float* __restrict__ out) {
#pragma clang fp contract(off)
  const int b = blockIdx.x;
  const int lane = threadIdx.x;

  __shared__ __align__(16) uint4 cellT[HW];  // {g, cm, hw, flg}
  __shared__ __align__(16) ull key2[HW];     // packed (f32keybits | 1023-idx)
  __shared__ __align__(16) unsigned par[HW]; // parent | mark bit31
  __shared__ __align__(16) ull level1[64];   // per-16-cell-group max
  const float2* cell2 = (const float2*)cellT; // {g, cm} pairs (stride 2)
  unsigned* cellu = (unsigned*)cellT;

  const float* cm = cm_g + b * HW;
  const float* sm = sm_g + b * HW;
  const float* gm = gm_g + b * HW;
  const float* om = om_g + b * HW;

  // ---- init pass 1: vectorized loads, locate goal/start ----
  float4 c4[4], o4[4];
  int gi = -1, si = -1;
#pragma unroll
  for (int q = 0; q < 4; ++q) {
    const int base = q * 256 + lane * 4;
    c4[q] = *(const float4*)(cm + base);
    o4[q] = *(const float4*)(om + base);
    const float4 s4 = *(const float4*)(sm + base);
    const float4 g4 = *(const float4*)(gm + base);
    const float sv[4] = {s4.x, s4.y, s4.z, s4.w};
    const float gv[4] = {g4.x, g4.y, g4.z, g4.w};
#pragma unroll
    for (int j = 0; j < 4; ++j) {
      if (gv[j] > 0.5f) gi = base + j;
      if (sv[j] > 0.5f) si = base + j;
    }
  }
#pragma unroll
  for (int m = 32; m >= 1; m >>= 1) {
    const int og = __shfl_xor(gi, m, 64);
    const int os = __shfl_xor(si, m, 64);
    gi = (og > gi) ? og : gi;
    si = (os > si) ? os : si;
  }
  const int goal = __builtin_amdgcn_readfirstlane(gi);
  const int start = __builtin_amdgcn_readfirstlane(si);

  // ---- init pass 2: h (exact ref op order), cell structs, key2, level1 ----
  level1[lane] = 0ull; // before the atomics below (same array: order kept)
  const float grf = (float)(goal >> 5), gcf = (float)(goal & 31);
#pragma unroll
  for (int q = 0; q < 4; ++q) {
    const int base = q * 256 + lane * 4;
    const float cv[4] = {c4[q].x, c4[q].y, c4[q].z, c4[q].w};
    const float ov[4] = {o4[q].x, o4[q].y, o4[q].z, o4[q].w};
    ull pk[4];
#pragma unroll
    for (int j = 0; j < 4; ++j) {
      const int cell = base + j;
      const float rr = (float)(cell >> 5), cc = (float)(cell & 31);
      const float dr = fabsf(rr - grf), dc = fabsf(cc - gcf);
      const float h0 = (dr + dc) - fminf(dr, dc); // exact (small ints)
      const float euc = sqrtf(dr * dr + dc * dc); // exact radicand
      const float t1 = 0.001f * euc;              // contract off: no fma
      const float hh = h0 + t1;
      const float hf = hh + cv[j]; // h_full (h + cm), exact ref order
      const float hw = 0.5f * hf;  // exact scaling
      unsigned fv = (ov[j] > 0.5f) ? 1u : 0u;
      pk[j] = (ull)(1023 - cell);
      if (cell == start) {
        fv |= 2u; // open = start map
        pk[j] = packkey(keyhalf(0.0f, hw), cell);
      }
      cellT[cell] = make_uint4(__float_as_uint(0.0f), __float_as_uint(cv[j]),
                               __float_as_uint(hw), fv);
      atomicMax(&level1[cell >> 4], pk[j]);
    }
    *(uint4*)&par[base] =
        make_uint4((unsigned)goal, (unsigned)goal, (unsigned)goal, (unsigned)goal);
    ulonglong2 k01, k23;
    k01.x = pk[0]; k01.y = pk[1];
    k23.x = pk[2]; k23.y = pk[3];
    *(ulonglong2*)&key2[base] = k01;
    *(ulonglong2*)&key2[base + 2] = k23;
  }
  __builtin_amdgcn_wave_barrier();
  ull stale = level1[lane]; // S_{-1} group maxes

  int dlt = 0;
  if (lane < 8) {
    const int k = (lane < 4) ? lane : lane + 1; // skip center
    dlt = (k / 3 - 1) * 32 + (k % 3 - 1);
  }

  int sel = start; // step-0 argmax: start is the only open cell
  bool reached = false;

#pragma unroll 1
  for (int step = 0; step < TMAXS; ++step) {
    if (sel == goal) { reached = true; break; }
    const int gp = sel >> 4;

    // scalar (SALU) neighbor-validity mask on uniform sel
    // lanes: 0,1,2 = top row; 0,3,5 = left col; 2,4,7 = right col;
    //        5,6,7 = bottom row
    const int sr = sel >> 5, sc = sel & 31;
    unsigned vmask = 0xFFu;
    if (sr == 0) vmask &= ~0x07u;
    if (sr == 31) vmask &= ~0xE0u;
    if (sc == 0) vmask &= ~0x29u;
    if (sc == 31) vmask &= ~0x94u;

    // -- issue all LDS reads first --
    const float2 sg = cell2[2 * sel]; // broadcast {g[sel], cm[sel]}
    const int n = sel + dlt;
    const bool relaxer = (lane < 8) && ((vmask >> lane) & 1u);
    uint4 nv = make_uint4(0u, 0u, 0u, 0u);
    if (relaxer) nv = cellT[n];
    const bool gcl = (lane >= 16) && (lane < 32);
    const int gcell = gp * 16 + (lane - 16);
    ull gco = 0ull;
    if (gcl) gco = key2[gcell];

    // -- chain A: 6-stage fold over stale' (register-only; hides under the
    //    LDS latency window) --
    double ma = (lane == gp) ? 0.0 : u2d(stale);
    ma = dpp_fmax64<0x111>(ma); // row_shr:1
    ma = dpp_fmax64<0x112>(ma); // row_shr:2
    ma = dpp_fmax64<0x114>(ma); // row_shr:4
    ma = dpp_fmax64<0x118>(ma); // row_shr:8
    ma = dpp_fmax64<0x142>(ma); // row_bcast:15
    ma = dpp_fmax64<0x143>(ma); // row_bcast:31 -> lane63 = max(all)

    // -- relax predicate + early cellT/par writes (pre-exp) --
    const float g2full = sg.x + sg.y;  // g[sel] + cm[sel], exact ref order
    const float g2h = 0.5f * g2full;   // exact scaling
    const unsigned f = nv.w;
    const bool updv =
        relaxer && (f & 1u) &&
        (((f & 6u) == 0u) || (((f & 2u) != 0u) && (__uint_as_float(nv.x) > g2full)));
    if (updv) {
      cellT[n] = make_uint4(__float_as_uint(g2full), nv.y, nv.z, f | 2u);
      par[n] = (unsigned)sel;
    }
    if (lane == 8) {
      cellu[4 * sel + 3] = 5u;          // pop: free|hist (validated const)
      key2[sel] = (ull)(1023 - sel);    // denormal entry
    }

    // -- chain C: 4-stage fold over patched group keys (NO exp dependency;
    //    runs while the exp chain is in flight) --
    ull gcp = gco;
    if (gcl && gcell == sel) gcp = (ull)(1023 - sel); // patch the pop
    double mc = gcl ? u2d(gcp) : 0.0;
    mc = dpp_fmax64<0x111>(mc); // row_shr:1
    mc = dpp_fmax64<0x112>(mc); // row_shr:2
    mc = dpp_fmax64<0x114>(mc); // row_shr:4
    mc = dpp_fmax64<0x118>(mc); // row_shr:8 -> lane31 = group max
    if (lane == 31) level1[gp] = d2u(mc); // rebuilt group max (single store)

    // -- pre-exp merge of the non-fresh side --
    const ull GC = rdl64(mc, 31);
    const ull MA = rdl64(ma, 63);
    const ull MACv = (GC > MA) ? GC : MA;

    // -- exp + pk + key2/level1 maintenance --
    ull pk = 0ull;
    if (updv) pk = packkey(keyhalf(g2h, __uint_as_float(nv.z)), n);
    if (updv) key2[n] = pk;
    if (updv) atomicMax(&level1[n >> 4], pk);
    const ull stale_n = level1[lane]; // after ALL level1 updates (in-order)

    // -- chain B: 3-stage fold over fresh pk (lanes 0..7) -> lane7 --
    double mb = updv ? u2d(pk) : 0.0;
    mb = dpp_fmax64<0x111>(mb); // row_shr:1
    mb = dpp_fmax64<0x112>(mb); // row_shr:2
    mb = dpp_fmax64<0x114>(mb); // row_shr:4 -> lane7 = max(lanes 0..7)
    const ull PB = rdl64(mb, 7);

    // -- final: one compare (u64 order == nonneg-f64 order, same ties) --
    const ull M = (PB > MACv) ? PB : MACv;
    sel = 1023 - (int)((unsigned)M & 1023u);
    stale = stale_n;
    __builtin_amdgcn_wave_barrier();
  }
  if (reached && lane == 0) cellu[4 * goal + 3] |= 4u; // hist includes goal
  __builtin_amdgcn_wave_barrier();

  // ---- fused backtrack (lane 0): mark path via par bit31 ----
  if (lane == 0) {
    const unsigned pv = par[goal];
    par[goal] = pv | 0x80000000u; // path starts as goal one-hot
    unsigned loc = pv & 1023u;
#pragma unroll 1
    for (int i = 0; i < HW; ++i) {
      const unsigned w = par[loc];
      if (w & 0x80000000u) break; // deterministic replay of marked cells
      par[loc] = w | 0x80000000u;
      loc = w & 1023u;
    }
  }
  __builtin_amdgcn_wave_barrier();

  // ---- epilogue: hist + path ----
#pragma unroll
  for (int q = 0; q < 4; ++q) {
    const int base = q * 256 + lane * 4;
    float4 hv, pv;
    hv.x = (cellu[4 * (base + 0) + 3] & 4u) ? 1.0f : 0.0f;
    hv.y = (cellu[4 * (base + 1) + 3] & 4u) ? 1.0f : 0.0f;
    hv.z = (cellu[4 * (base + 2) + 3] & 4u) ? 1.0f : 0.0f;
    hv.w = (cellu[4 * (base + 3) + 3] & 4u) ? 1.0f : 0.0f;
    pv.x = (par[base + 0] >> 31) ? 1.0f : 0.0f;
    pv.y = (par[base + 1] >> 31) ? 1.0f : 0.0f;
    pv.z = (par[base + 2] >> 31) ? 1.0f : 0.0f;
    pv.w = (par[base + 3] >> 31) ? 1.0f : 0.0f;
    *(float4*)(out + b * HW + base) = hv;
    *(float4*)(out + NB * HW + b * HW + base) = pv;
  }
}

extern "C" void kernel_launch(void* const* d_in, const int* in_sizes, int n_in,
                              void* d_out, int out_size, void* d_ws,
                              size_t ws_size, hipStream_t stream) {
  const float* cm = (const float*)d_in[0];
  const float* sm = (const float*)d_in[1];
  const float* gm = (const float*)d_in[2];
  const float* om = (const float*)d_in[3];
  float* out = (float*)d_out;
  hipLaunchKernelGGL(astar_fused, dim3(NB), dim3(64), 0, stream, cm, sm, gm,
                     om, out);
}